// Round 3
// baseline (452.136 us; speedup 1.0000x reference)
//
#include <hip/hip_runtime.h>
#include <math.h>

// ---------------------------------------------------------------------------
// REFT_Psi: B=65536 rows, DIM=64.
//  kA  : (grid 2, dir-split) mem-attn -> o_vec -> per-gate GRU constants;
//        G/V/pisq; zeroes WS_STRESS.
//  kW  : packs all small weights to fp16 in ws (ctxw, logits-bw, emo w1/w2,
//        GRU WRZ/WN/WHN per dir).  (fused path only)
//  kB1 : BARRIER-FREE fused kernel. Each wave owns 16 rows end-to-end:
//        ctx GEMM (A direct from global, B fp16 from ws) -> logits+tpe GEMM
//        -> a0 diag -> emotion MLP -> raw e -> per-row epilogue.  All LDS
//        wave-private (per-wave 5632B slice + wave-local cxout rows).
//        Stress: per-wave shfl reduce + atomicAdd.
//  [kE : fallback only: O2 += 0.001*stress]
//  kC  : bi-GRU via MFMA; B-fragments straight from fp16 weights in ws
//        (no weight LDS -> 4 blocks/CU); scalar stress folded as
//        sc*rowsum(Wih_e) into cg2; depth-2 reg staging; dir0 writes
//        e_theta and theta_next.
// ---------------------------------------------------------------------------

#define BATCH 65536
#define CTXD  384
#define NP    5
#define EPSV  1e-8f

typedef _Float16 h8 __attribute__((ext_vector_type(8)));
typedef _Float16 h4 __attribute__((ext_vector_type(4)));
typedef float f32x4 __attribute__((ext_vector_type(4)));
typedef float f4a __attribute__((ext_vector_type(4)));                 // 16B-aligned
typedef float f4u __attribute__((ext_vector_type(4), aligned(4)));     // 4B-aligned

// output offsets (floats)
#define O0 0
#define O1 4194304
#define O2 12582912
#define O3 16777216
#define O4 16842752
#define O5 16908288

// workspace offsets (floats)
#define WS_STRESS 0
#define WS_GICF   1536
#define WS_GICR   1792
#define WS_G      2048   // 25 floats: pe@pe^T
#define WS_V      2080   // 5 floats: pe@prev_ideal
#define WS_PISQ   2088   // 1 float
#define WS_H16F   4096   // fp16 packed weights region (46080 floats)
// halves offsets inside the fp16 region:
#define HCXW  0          // [64][384]   ctx_w
#define HBW   24576      // [16][128]   logits rows: 0-4 iw, 5-9 pe-hi, 10-14 pe-lo
#define HW1   26624      // [128][64]   emo w1
#define HW2   34816      // [64][128]   emo w2
#define HGRU  43008      // per dir 24576: [128][128] (wih_e|whh) | [64][64] WN | [64][64] WHN
#define HTOT  92160
#define WS_E  50176      // raw emotion e [B*64] (fused path only)

__device__ __forceinline__ float sigmoidf_(float x) {
  return 1.f / (1.f + __expf(-x));
}
__device__ __forceinline__ float tanhf_(float x) {
  float e2 = __expf(-2.f * x);
  return 2.f / (1.f + e2) - 1.f;
}
__device__ __forceinline__ h4 cvt4v(f4a v) {
  h4 o = {(_Float16)v[0], (_Float16)v[1], (_Float16)v[2], (_Float16)v[3]};
  return o;
}
__device__ __forceinline__ h8 pack8(f4a u0, f4a u1) {
  h8 b = {(_Float16)u0[0], (_Float16)u0[1], (_Float16)u0[2], (_Float16)u0[3],
          (_Float16)u1[0], (_Float16)u1[1], (_Float16)u1[2], (_Float16)u1[3]};
  return b;
}
__device__ __forceinline__ h8 cvt8p(const float* p) {
  return pack8(*(const f4a*)p, *(const f4a*)(p + 4));
}
__device__ __forceinline__ h8 ldh8(const _Float16* p) { return *(const h8*)p; }

// ---------------------------------------------------------------- kernel A
// grid 2: block 0 = fwd GIC + G/V/pisq + stress zero, block 1 = rev GIC.
__global__ __launch_bounds__(256) void kA(
    const float* __restrict__ memory, const float* __restrict__ tw,
    const float* __restrict__ ipw, const float* __restrict__ ipb,
    const float* __restrict__ outw, const float* __restrict__ outb,
    const float* __restrict__ wihf, const float* __restrict__ bihf,
    const float* __restrict__ wihr, const float* __restrict__ bihr,
    const float* __restrict__ pe, const float* __restrict__ pi,
    float* __restrict__ ws)
{
  __shared__ __align__(16) float attn[16], mth[64], vv[64], ov[64];
  int t = threadIdx.x;
  int dir = blockIdx.x;
  if (t == 0) {
    float m = tw[0];
#pragma unroll
    for (int i = 1; i < 10; i++) m = fmaxf(m, tw[i]);
    float e[10]; float s = 0.f;
#pragma unroll
    for (int i = 0; i < 10; i++) { e[i] = __expf(tw[i] - m); s += e[i]; }
#pragma unroll
    for (int i = 0; i < 10; i++) attn[i] = e[i] / s;
  }
  if (dir == 0) {
    if (t < 25) {
      int l = t / 5, m2 = t - l * 5;
      const f4a* pa = (const f4a*)(pe + l * 64);
      const f4a* pb = (const f4a*)(pe + m2 * 64);
      float s = 0.f;
#pragma unroll
      for (int j = 0; j < 16; j++) {
        f4a a = pa[j], b = pb[j];
        s += a[0]*b[0] + a[1]*b[1] + a[2]*b[2] + a[3]*b[3];
      }
      ws[WS_G + t] = s;
    } else if (t >= 32 && t < 37) {
      int l = t - 32;
      const f4a* pa = (const f4a*)(pe + l * 64);
      const f4a* pb = (const f4a*)pi;
      float s = 0.f;
#pragma unroll
      for (int j = 0; j < 16; j++) {
        f4a a = pa[j], b = pb[j];
        s += a[0]*b[0] + a[1]*b[1] + a[2]*b[2] + a[3]*b[3];
      }
      ws[WS_V + l] = s;
    } else if (t == 40) {
      const f4a* pb = (const f4a*)pi;
      float s = 0.f;
#pragma unroll
      for (int j = 0; j < 16; j++) {
        f4a b = pb[j];
        s += b[0]*b[0] + b[1]*b[1] + b[2]*b[2] + b[3]*b[3];
      }
      ws[WS_PISQ] = s;
    } else if (t == 41) {
      ws[WS_STRESS] = 0.f;    // kB1 accumulates atomically
    }
  }
  __syncthreads();
  if (t < 64) {
    float a = 0.f;
#pragma unroll
    for (int m = 0; m < 10; m++) a += attn[m] * memory[m * 64 + t];
    mth[t] = a;
  }
  __syncthreads();
  if (t < 64) {
    const f4a* wr = (const f4a*)(ipw + (size_t)(128 + t) * 64);
    const f4a* mv = (const f4a*)mth;
    float a = ipb[128 + t];
#pragma unroll
    for (int j = 0; j < 16; j++) {
      f4a w = wr[j], o = mv[j];
      a += w[0]*o[0] + w[1]*o[1] + w[2]*o[2] + w[3]*o[3];
    }
    vv[t] = a;
  }
  __syncthreads();
  if (t < 64) {
    const f4a* wr = (const f4a*)(outw + (size_t)t * 64);
    const f4a* mv = (const f4a*)vv;
    float a = outb[t];
#pragma unroll
    for (int j = 0; j < 16; j++) {
      f4a w = wr[j], o = mv[j];
      a += w[0]*o[0] + w[1]*o[1] + w[2]*o[2] + w[3]*o[3];
    }
    ov[t] = a;
  }
  __syncthreads();
  if (t < 192) {
    const float* WIH = dir ? wihr : wihf;
    const float* BIH = dir ? bihr : bihf;
    float a = BIH[t];
    const f4a* ovv = (const f4a*)ov;
#pragma unroll
    for (int j = 0; j < 16; j++) {
      f4u w = *(const f4u*)(WIH + (size_t)t * 130 + j * 4);
      f4a o = ovv[j];
      a += w[0]*o[0] + w[1]*o[1] + w[2]*o[2] + w[3]*o[3];
    }
    ws[(dir ? WS_GICR : WS_GICF) + t] = a;
  }
}

// ---------------------------------------------------------------- kernel W
// Packs all small weights to fp16 into ws (grid 360 x 256 = 92160 halves).
__global__ __launch_bounds__(256) void kW(
    const float* __restrict__ cw, const float* __restrict__ iw,
    const float* __restrict__ pe,
    const float* __restrict__ w1, const float* __restrict__ w2,
    const float* __restrict__ wihf, const float* __restrict__ whhf,
    const float* __restrict__ wihr, const float* __restrict__ whhr,
    float* __restrict__ ws)
{
  _Float16* hv = (_Float16*)(ws + WS_H16F);
  int i = blockIdx.x * 256 + threadIdx.x;
  _Float16 v;
  if (i < HBW) {                                   // ctxw [64][384]
    v = (_Float16)cw[i];
  } else if (i < HW1) {                            // logits bw [16][128]
    int i2 = i - HBW;
    int r = i2 >> 7, k = i2 & 127;
    float f = 0.f;
    if (r < 5) f = iw[r * 128 + k];
    else if (r < 10) { if (k < 64) f = pe[(r - 5) * 64 + k]; }
    else if (r < 15) {
      if (k < 64) { float p = pe[(r - 10) * 64 + k]; f = p - (float)(_Float16)p; }
    }
    v = (_Float16)f;
  } else if (i < HW2) {                            // w1 [128][64]
    v = (_Float16)w1[i - HW1];
  } else if (i < HGRU) {                           // w2 [64][128]
    v = (_Float16)w2[i - HW2];
  } else {                                         // GRU, per dir
    int j = i - HGRU;
    int dir = j >= 24576;
    int i2 = j - (dir ? 24576 : 0);
    const float* WIH = dir ? wihr : wihf;
    const float* WHH = dir ? whhr : whhf;
    float f;
    if (i2 < 16384) {
      int n = i2 >> 7, k = i2 & 127;
      f = (k < 64) ? WIH[n * 130 + 64 + k] : WHH[n * 64 + (k - 64)];
    } else if (i2 < 20480) {
      int j2 = i2 - 16384; int n = j2 >> 6, k = j2 & 63;
      f = WIH[(128 + n) * 130 + 64 + k];
    } else {
      int j2 = i2 - 20480; int n = j2 >> 6, k = j2 & 63;
      f = WHH[(128 + n) * 64 + k];
    }
    v = (_Float16)f;
  }
  hv[i] = v;
}

// ---------------------------------------------------------------- kernel B1
// grid 1024, block 256 (4 waves), 64 rows/block, 16 rows/wave.
// ZERO __syncthreads: every LDS buffer is wave-private.
// Per-wave 5632B slice in R: phase A = tthhi[16][72] | tthlo[16][72];
// phase B (aliased) = mid[16][136] | Lb[16][17] f32 | a0b[16] f32.
// cxout[64][72] is wave-local by rows.  LDS total 22528+9216 = 31744 B.
template <int FUSED>
__global__ __launch_bounds__(256, 4) void kB1(
    const float* __restrict__ theta, const float* __restrict__ context,
    const float* __restrict__ ctxw, const float* __restrict__ ctxb,
    const float* __restrict__ idealw, const float* __restrict__ idealb,
    const float* __restrict__ pe,
    const float* __restrict__ w1, const float* __restrict__ b1,
    const float* __restrict__ w2, const float* __restrict__ b2,
    const float* __restrict__ fw, const float* __restrict__ fb,
    float* __restrict__ dout, float* __restrict__ ws,
    float* __restrict__ eout)
{
  __shared__ __align__(16) char R[4 * 5632];
  __shared__ __align__(16) _Float16 cxout[64 * 72];

  int t = threadIdx.x, lane = t & 63, wv = t >> 6;
  int q = lane >> 4, c = lane & 15;
  int Rbase = blockIdx.x << 6;
  int wrow = Rbase + 16 * wv;          // wave's first global row

  char* Rw = R + wv * 5632;
  _Float16* tthhi = (_Float16*)Rw;                 // [16][72]
  _Float16* tthlo = (_Float16*)(Rw + 2304);        // [16][72]
  _Float16* mid   = (_Float16*)Rw;                 // [16][136]
  float*    Lb    = (float*)(Rw + 4352);           // [16][17]
  float*    a0b   = (float*)(Rw + 5440);           // [16]

  const _Float16* hv   = (const _Float16*)(ws + WS_H16F);
  const _Float16* hcxw = hv + HCXW;
  const _Float16* hbw  = hv + HBW;
  const _Float16* hw1  = hv + HW1;
  const _Float16* hw2  = hv + HW2;

  // ---- issue theta loads (wave-local rows) ----
  const f4a* ts = (const f4a*)(theta + (size_t)wrow * 64);
  f4a th0 = ts[lane], th1 = ts[lane + 64], th2 = ts[lane + 128], th3 = ts[lane + 192];

  // ---- issue ctx A-fragment batch 1 (ks 0..5) ----
  const float* crow = context + (size_t)(wrow + c) * CTXD + q * 8;
  f4a a0_[6], a1_[6];
#pragma unroll
  for (int ks = 0; ks < 6; ++ks) {
    a0_[ks] = *(const f4a*)(crow + ks * 32);
    a1_[ks] = *(const f4a*)(crow + ks * 32 + 4);
  }

  // ---- stage theta hi/lo (wave-local; in-wave DS ordering only) ----
  {
#define TST(j, sj) { int sl = (j) * 64 + lane; int row = sl >> 4, pos = sl & 15; \
    h4 hi = cvt4v(sj); \
    f4a lo = {sj[0] - (float)hi[0], sj[1] - (float)hi[1], \
              sj[2] - (float)hi[2], sj[3] - (float)hi[3]}; \
    *(h4*)&tthhi[row * 72 + pos * 4] = hi; \
    *(h4*)&tthlo[row * 72 + pos * 4] = cvt4v(lo); }
    TST(0, th0) TST(1, th1) TST(2, th2) TST(3, th3)
#undef TST
  }

  // ---- convert batch 1, issue+convert batch 2 ----
  h8 af[12];
#pragma unroll
  for (int ks = 0; ks < 6; ++ks) af[ks] = pack8(a0_[ks], a1_[ks]);
#pragma unroll
  for (int ks = 0; ks < 6; ++ks) {
    a0_[ks] = *(const f4a*)(crow + (ks + 6) * 32);
    a1_[ks] = *(const f4a*)(crow + (ks + 6) * 32 + 4);
  }
#pragma unroll
  for (int ks = 0; ks < 6; ++ks) af[6 + ks] = pack8(a0_[ks], a1_[ks]);

  // ---- ctx GEMM: wave owns rows, loops over 4 N-tiles ----
#pragma unroll
  for (int tn = 0; tn < 4; ++tn) {
    f32x4 acc = (f32x4)(0.f);
#pragma unroll
    for (int ks = 0; ks < 12; ++ks) {
      h8 b;
      if constexpr (FUSED) b = ldh8(hcxw + (size_t)(tn * 16 + c) * CTXD + ks * 32 + q * 8);
      else                 b = cvt8p(ctxw + (size_t)(tn * 16 + c) * CTXD + ks * 32 + q * 8);
      acc = __builtin_amdgcn_mfma_f32_16x16x32_f16(af[ks], b, acc, 0, 0, 0);
    }
    float cb = ctxb[tn * 16 + c];
#pragma unroll
    for (int reg = 0; reg < 4; ++reg)
      cxout[(16 * wv + q * 4 + reg) * 72 + tn * 16 + c] = (_Float16)(acc[reg] + cb);
  }

  // ---- B-fragments for logits/tpe GEMM ----
  h8 bw[4];
  if constexpr (FUSED) {
#pragma unroll
    for (int ks = 0; ks < 4; ++ks) bw[ks] = ldh8(hbw + c * 128 + ks * 32 + q * 8);
  } else {
#pragma unroll
    for (int ks = 0; ks < 4; ++ks) {
#pragma unroll
      for (int j = 0; j < 8; ++j) {
        int k = ks * 32 + q * 8 + j;
        float v = 0.f;
        if (c < 5) v = idealw[c * 128 + k];
        else if (c < 10) { if (k < 64) v = pe[(c - 5) * 64 + k]; }
        else if (c < 15) {
          if (k < 64) { float p = pe[(c - 10) * 64 + k]; v = p - (float)(_Float16)p; }
        }
        bw[ks][j] = (_Float16)v;
      }
    }
  }

  // ---- A-fragments (wave-local rows; in-wave DS ordering) ----
  const _Float16* ahp = &tthhi[c * 72 + q * 8];
  const _Float16* alp = &tthlo[c * 72 + q * 8];
  const _Float16* acp = &cxout[(16 * wv + c) * 72 + q * 8];
  h8 ah0 = *(const h8*)(ahp);
  h8 ah1 = *(const h8*)(ahp + 32);
  h8 al0 = *(const h8*)(alp);
  h8 al1 = *(const h8*)(alp + 32);
  h8 ac0 = *(const h8*)(acp);
  h8 ac1 = *(const h8*)(acp + 32);

  // logits + tpe (K = [theta(64) | cx(64)], lo-pass on theta half)
  f32x4 Lacc = (f32x4)(0.f);
  Lacc = __builtin_amdgcn_mfma_f32_16x16x32_f16(ah0, bw[0], Lacc, 0, 0, 0);
  Lacc = __builtin_amdgcn_mfma_f32_16x16x32_f16(ah1, bw[1], Lacc, 0, 0, 0);
  Lacc = __builtin_amdgcn_mfma_f32_16x16x32_f16(ac0, bw[2], Lacc, 0, 0, 0);
  Lacc = __builtin_amdgcn_mfma_f32_16x16x32_f16(ac1, bw[3], Lacc, 0, 0, 0);
  Lacc = __builtin_amdgcn_mfma_f32_16x16x32_f16(al0, bw[0], Lacc, 0, 0, 0);
  Lacc = __builtin_amdgcn_mfma_f32_16x16x32_f16(al1, bw[1], Lacc, 0, 0, 0);
  // (writes into Lb alias the tail of tthlo -- safe: all tth DS reads above
  //  are issued before these DS writes, and a wave's DS ops are in-order)
#pragma unroll
  for (int reg = 0; reg < 4; ++reg)
    Lb[(q * 4 + reg) * 17 + c] = Lacc[reg];

  // a0 = ||theta||^2 via diag: hi.hi + 2 hi.lo
  {
    f32x4 hh = (f32x4)(0.f), hl = (f32x4)(0.f);
    hh = __builtin_amdgcn_mfma_f32_16x16x32_f16(ah0, ah0, hh, 0, 0, 0);
    hh = __builtin_amdgcn_mfma_f32_16x16x32_f16(ah1, ah1, hh, 0, 0, 0);
    hl = __builtin_amdgcn_mfma_f32_16x16x32_f16(ah0, al0, hl, 0, 0, 0);
    hl = __builtin_amdgcn_mfma_f32_16x16x32_f16(ah1, al1, hl, 0, 0, 0);
    if ((lane >> 4) == ((lane & 15) >> 2)) {
      int j = lane & 15;
      a0b[j] = hh[j & 3] + 2.f * hl[j & 3];
    }
  }

  // ---- emotion MLP layer 1 (reuses ah0/ah1) ----
#pragma unroll
  for (int tn = 0; tn < 8; ++tn) {
    h8 b0, b1f;
    if constexpr (FUSED) {
      b0  = ldh8(hw1 + (size_t)(tn * 16 + c) * 64 + q * 8);
      b1f = ldh8(hw1 + (size_t)(tn * 16 + c) * 64 + 32 + q * 8);
    } else {
      b0  = cvt8p(w1 + (size_t)(tn * 16 + c) * 64 + q * 8);
      b1f = cvt8p(w1 + (size_t)(tn * 16 + c) * 64 + 32 + q * 8);
    }
    f32x4 a = (f32x4)(0.f);
    a = __builtin_amdgcn_mfma_f32_16x16x32_f16(ah0, b0, a, 0, 0, 0);
    a = __builtin_amdgcn_mfma_f32_16x16x32_f16(ah1, b1f, a, 0, 0, 0);
    float bv = b1[tn * 16 + c];
#pragma unroll
    for (int reg = 0; reg < 4; ++reg)
      mid[(q * 4 + reg) * 136 + tn * 16 + c] = (_Float16)tanhf_(a[reg] + bv);
  }

  // ---- MLP layer 2 (wave-local mid) -> raw e ----
  {
    const _Float16* am = &mid[c * 136 + q * 8];
    h8 m0 = *(const h8*)(am);
    h8 m1 = *(const h8*)(am + 32);
    h8 m2 = *(const h8*)(am + 64);
    h8 m3 = *(const h8*)(am + 96);
#pragma unroll
    for (int tn = 0; tn < 4; ++tn) {
      f32x4 a = (f32x4)(0.f);
#pragma unroll
      for (int ks = 0; ks < 4; ++ks) {
        h8 b;
        if constexpr (FUSED) b = ldh8(hw2 + (size_t)(tn * 16 + c) * 128 + ks * 32 + q * 8);
        else                 b = cvt8p(w2 + (size_t)(tn * 16 + c) * 128 + ks * 32 + q * 8);
        h8 av = (ks == 0) ? m0 : (ks == 1) ? m1 : (ks == 2) ? m2 : m3;
        a = __builtin_amdgcn_mfma_f32_16x16x32_f16(av, b, a, 0, 0, 0);
      }
      float bv = b2[tn * 16 + c];
#pragma unroll
      for (int reg = 0; reg < 4; ++reg) {
        int row = wrow + q * 4 + reg;
        eout[((size_t)row << 6) + tn * 16 + c] = fmaxf(a[reg] + bv, 0.f);  // raw e
      }
    }
  }

  // ---- per-row epilogue (lanes 0-15 own rows wrow+lane) ----
  if (lane < 16) {
    int row = wrow + lane;
    float L[NP], tpe[NP];
#pragma unroll
    for (int l = 0; l < NP; l++) {
      L[l]   = Lb[lane * 17 + l] + idealb[l];
      tpe[l] = Lb[lane * 17 + 5 + l] + Lb[lane * 17 + 10 + l];
    }
    float mx = L[0];
#pragma unroll
    for (int l = 1; l < NP; l++) mx = fmaxf(mx, L[l]);
    float P[NP], s = 0.f;
#pragma unroll
    for (int l = 0; l < NP; l++) { P[l] = __expf(L[l] - mx); s += P[l]; }
    float inv = 1.f / s;
#pragma unroll
    for (int l = 0; l < NP; l++) P[l] *= inv;
#pragma unroll
    for (int l = 0; l < NP; l++) dout[O5 + (size_t)row * NP + l] = P[l];

    float a2 = 0.f, tipi = 0.f;
#pragma unroll
    for (int l = 0; l < NP; l++) {
      a2   += P[l] * tpe[l];
      tipi += P[l] * ws[WS_V + l];
    }
    float a1 = 0.f;
#pragma unroll
    for (int l = 0; l < NP; l++) {
      float pl = P[l];
#pragma unroll
      for (int m = 0; m < NP; m++) a1 += pl * P[m] * ws[WS_G + l * 5 + m];
    }
    float a0 = a0b[lane];
    float a3 = fmaxf(a1 - 2.f * tipi + ws[WS_PISQ], 0.f);

    float na = sqrtf(a0), nb = sqrtf(a1);
    float qq = 1.f / ((na + EPSV) * (nb + EPSV));
    float num = a2 * qq;
    float den = fmaxf(na * nb * qq, EPSV);
    dout[O3 + row] = num / den;
    float fq = sqrtf(a3);
    float om = tanhf_(fq * fw[0] + fb[0]) * (1.f + 0.1f * __sinf(fq));
    dout[O4 + row] = om;

    // stress partial: reduce across the 16 active lanes, one atomic per wave
    float p = a0 - 2.f * a2 + a1;
    p += __shfl_xor(p, 1, 64);
    p += __shfl_xor(p, 2, 64);
    p += __shfl_xor(p, 4, 64);
    p += __shfl_xor(p, 8, 64);
    if (lane == 0) atomicAdd(&ws[WS_STRESS], p);
  }
}

// ---------------------------------------------------------------- kernel E (fallback only)
__global__ __launch_bounds__(256) void kE(float* __restrict__ dout,
                                          const float* __restrict__ ws)
{
  float sc = 0.001f * ws[WS_STRESS];
  int i = blockIdx.x * 256 + threadIdx.x;
  float4* p = (float4*)(dout + O2);
  float4 v = p[i];
  v.x += sc; v.y += sc; v.z += sc; v.w += sc;
  p[i] = v;
}

// ---------------------------------------------------------------- kernel C
// MFMA bi-GRU. grid (256, 2): bx covers 256 rows (4 M-tiles of 64), by=dir.
// FUSED: B-fragments straight from fp16 weights in ws (L2-hot) -> LDS is
// ABuf only (~20 KB) -> 4 blocks/CU.  Scalar stress folded as
// sc*rowsum(Wih_e) into cg2 (exact fp32 rank-1).  Depth-2 reg staging.
template <int FUSED>
__global__ __launch_bounds__(256, 4) void kC(
    const float* __restrict__ theta, const float* __restrict__ hprev,
    const float* __restrict__ wihf, const float* __restrict__ whhf,
    const float* __restrict__ bhhf,
    const float* __restrict__ wihr, const float* __restrict__ whhr,
    const float* __restrict__ bhhr,
    const float* __restrict__ ws, const float* __restrict__ esrc,
    float* __restrict__ dout)
{
  __shared__ __align__(16) _Float16 WRZ[FUSED ? 8 : 128 * 136];
  __shared__ __align__(16) _Float16 WNl[FUSED ? 8 : 64 * 72];
  __shared__ __align__(16) _Float16 WHNl[FUSED ? 8 : 64 * 72];
  __shared__ __align__(16) _Float16 ABuf[64 * 136];
  __shared__ float cg2[192], wre[192], wom[192], bhn[64];
  __shared__ float rLDS[64], oLDS[64];

  int t = threadIdx.x, lane = t & 63, wv = t >> 6;
  int q = lane >> 4, col = lane & 15;
  int dir = blockIdx.y;
  const float* WIH = dir ? wihr : wihf;
  const float* WHH = dir ? whhr : whhf;
  const float* BHH = dir ? bhhr : bhhf;
  const float* GIC = ws + (dir ? WS_GICR : WS_GICF);
  float sc = 0.001f * ws[WS_STRESS];

  const _Float16* gw  = (const _Float16*)(ws + WS_H16F) + HGRU + dir * 24576;
  const _Float16* gRZ = gw;            // [128][128]
  const _Float16* gN  = gw + 16384;    // [64][64]
  const _Float16* gHN = gw + 20480;    // [64][64]

  if constexpr (!FUSED) {
    // ---- weight staging to LDS (fallback path) ----
    for (int idx = t; idx < 128 * 32; idx += 256) {
      int n = idx >> 5, g = idx & 31;
      if (g < 16) {
        f4u v = *(const f4u*)(WIH + (size_t)n * 130 + 64 + g * 4);
        h4 o = {(_Float16)v[0], (_Float16)v[1], (_Float16)v[2], (_Float16)v[3]};
        *(h4*)&WRZ[n * 136 + g * 4] = o;
      } else {
        f4a v = *(const f4a*)(WHH + (size_t)n * 64 + (g - 16) * 4);
        *(h4*)&WRZ[n * 136 + 64 + (g - 16) * 4] = cvt4v(v);
      }
    }
    for (int idx = t; idx < 64 * 32; idx += 256) {
      int n = idx >> 5, g = idx & 31;
      if (g < 16) {
        f4u v = *(const f4u*)(WIH + (size_t)(128 + n) * 130 + 64 + g * 4);
        h4 o = {(_Float16)v[0], (_Float16)v[1], (_Float16)v[2], (_Float16)v[3]};
        *(h4*)&WNl[n * 72 + g * 4] = o;
      } else {
        f4a v = *(const f4a*)(WHH + (size_t)(128 + n) * 64 + (g - 16) * 4);
        *(h4*)&WHNl[n * 72 + (g - 16) * 4] = cvt4v(v);
      }
    }
  }
  if (t < 192) {
    float s = 0.f;
#pragma unroll
    for (int j = 0; j < 16; j++) {
      f4u w = *(const f4u*)(WIH + (size_t)t * 130 + 64 + j * 4);
      s += w[0] + w[1] + w[2] + w[3];
    }
    wre[t] = WIH[t * 130 + 128];
    wom[t] = WIH[t * 130 + 129];
    cg2[t] = GIC[t] + (t < 128 ? BHH[t] : 0.f) + sc * s;
  }
  if (t < 64) bhn[t] = BHH[128 + t];

  int Mb0 = blockIdx.x << 8;
  f4a rea0, rea1, rea2, rea3, rha0, rha1, rha2, rha3;
  f4a reb0, reb1, reb2, reb3, rhb0, rhb1, rhb2, rhb3;
  float rva = 0.f, ova = 0.f, rvb = 0.f, ovb = 0.f;

#define STAGE_LOAD(S, mb) do { \
    const f4a* e4 = (const f4a*)(esrc + ((size_t)(mb) << 6)); \
    const f4a* hp4 = (const f4a*)(hprev + (size_t)dir * (BATCH * 64) + ((size_t)(mb) << 6)); \
    re##S##0 = e4[t]; re##S##1 = e4[t + 256]; re##S##2 = e4[t + 512]; re##S##3 = e4[t + 768]; \
    rh##S##0 = hp4[t]; rh##S##1 = hp4[t + 256]; rh##S##2 = hp4[t + 512]; rh##S##3 = hp4[t + 768]; \
    if (t < 64) { rv##S = dout[O3 + (mb) + t]; ov##S = dout[O4 + (mb) + t]; } \
  } while (0)

#define ST1(j, rej, rhj, mb) do { \
    int idx = t + (j) * 256; int row = idx >> 4, p4 = idx & 15; \
    f4a ev = rej; \
    if (!FUSED) { ev[0] -= sc; ev[1] -= sc; ev[2] -= sc; ev[3] -= sc; } \
    *(h4*)&ABuf[row * 136 + p4 * 4] = cvt4v(ev); \
    *(h4*)&ABuf[row * 136 + 64 + p4 * 4] = cvt4v(rhj); \
    if (FUSED && dir == 0) { \
      f4a et = ev; et[0] += sc; et[1] += sc; et[2] += sc; et[3] += sc; \
      ((f4a*)(dout + O2))[((size_t)(mb) << 4) + idx] = et; \
    } \
  } while (0)

#define STAGE_WRITE(S, mb) do { \
    ST1(0, re##S##0, rh##S##0, mb); ST1(1, re##S##1, rh##S##1, mb); \
    ST1(2, re##S##2, rh##S##2, mb); ST1(3, re##S##3, rh##S##3, mb); \
    if (t < 64) { rLDS[t] = rv##S; oLDS[t] = ov##S; } \
  } while (0)

  auto compute = [&](int Mbase) {
    const _Float16* arow = &ABuf[(16 * wv + col) * 136 + q * 8];
    h8 a0 = *(const h8*)(arow);
    h8 a1 = *(const h8*)(arow + 32);
    h8 a2 = *(const h8*)(arow + 64);
    h8 a3 = *(const h8*)(arow + 96);

    f32x4 accR[4], accZ[4], accN[4], accH[4];
#pragma unroll
    for (int td = 0; td < 4; td++) {
      accR[td] = (f32x4)(0.f); accZ[td] = (f32x4)(0.f);
      accN[td] = (f32x4)(0.f); accH[td] = (f32x4)(0.f);
    }
#pragma unroll
    for (int td = 0; td < 4; td++) {
      h8 r0, r1, r2, r3, z0, z1, z2, z3, n0, n1, hh0, hh1;
      if constexpr (FUSED) {
        const _Float16* br = gRZ + (size_t)(td * 16 + col) * 128 + q * 8;
        r0 = ldh8(br); r1 = ldh8(br + 32); r2 = ldh8(br + 64); r3 = ldh8(br + 96);
        const _Float16* bz = gRZ + (size_t)(64 + td * 16 + col) * 128 + q * 8;
        z0 = ldh8(bz); z1 = ldh8(bz + 32); z2 = ldh8(bz + 64); z3 = ldh8(bz + 96);
        const _Float16* bn = gN + (size_t)(td * 16 + col) * 64 + q * 8;
        n0 = ldh8(bn); n1 = ldh8(bn + 32);
        const _Float16* bh = gHN + (size_t)(td * 16 + col) * 64 + q * 8;
        hh0 = ldh8(bh); hh1 = ldh8(bh + 32);
      } else {
        const _Float16* br = &WRZ[(td * 16 + col) * 136 + q * 8];
        r0 = ldh8(br); r1 = ldh8(br + 32); r2 = ldh8(br + 64); r3 = ldh8(br + 96);
        const _Float16* bz = &WRZ[(64 + td * 16 + col) * 136 + q * 8];
        z0 = ldh8(bz); z1 = ldh8(bz + 32); z2 = ldh8(bz + 64); z3 = ldh8(bz + 96);
        const _Float16* bn = &WNl[(td * 16 + col) * 72 + q * 8];
        n0 = ldh8(bn); n1 = ldh8(bn + 32);
        const _Float16* bh = &WHNl[(td * 16 + col) * 72 + q * 8];
        hh0 = ldh8(bh); hh1 = ldh8(bh + 32);
      }
      accR[td] = __builtin_amdgcn_mfma_f32_16x16x32_f16(a0, r0, accR[td], 0, 0, 0);
      accR[td] = __builtin_amdgcn_mfma_f32_16x16x32_f16(a1, r1, accR[td], 0, 0, 0);
      accR[td] = __builtin_amdgcn_mfma_f32_16x16x32_f16(a2, r2, accR[td], 0, 0, 0);
      accR[td] = __builtin_amdgcn_mfma_f32_16x16x32_f16(a3, r3, accR[td], 0, 0, 0);
      accZ[td] = __builtin_amdgcn_mfma_f32_16x16x32_f16(a0, z0, accZ[td], 0, 0, 0);
      accZ[td] = __builtin_amdgcn_mfma_f32_16x16x32_f16(a1, z1, accZ[td], 0, 0, 0);
      accZ[td] = __builtin_amdgcn_mfma_f32_16x16x32_f16(a2, z2, accZ[td], 0, 0, 0);
      accZ[td] = __builtin_amdgcn_mfma_f32_16x16x32_f16(a3, z3, accZ[td], 0, 0, 0);
      accN[td] = __builtin_amdgcn_mfma_f32_16x16x32_f16(a0, n0, accN[td], 0, 0, 0);
      accN[td] = __builtin_amdgcn_mfma_f32_16x16x32_f16(a1, n1, accN[td], 0, 0, 0);
      accH[td] = __builtin_amdgcn_mfma_f32_16x16x32_f16(a2, hh0, accH[td], 0, 0, 0);
      accH[td] = __builtin_amdgcn_mfma_f32_16x16x32_f16(a3, hh1, accH[td], 0, 0, 0);
    }

#pragma unroll
    for (int reg = 0; reg < 4; reg++) {
      int lr  = 16 * wv + q * 4 + reg;
      int row = Mbase + lr;
      float rv = rLDS[lr], ovv = oLDS[lr];
#pragma unroll
      for (int td = 0; td < 4; td++) {
        int d = td * 16 + col;
        float hvv = (float)ABuf[lr * 136 + 64 + d];
        float A0 = accR[td][reg] + cg2[d]       + rv * wre[d]       + ovv * wom[d];
        float A1 = accZ[td][reg] + cg2[64 + d]  + rv * wre[64 + d]  + ovv * wom[64 + d];
        float AN = accN[td][reg] + cg2[128 + d] + rv * wre[128 + d] + ovv * wom[128 + d];
        float AH = accH[td][reg] + bhn[d];
        float r  = sigmoidf_(A0);
        float z  = sigmoidf_(A1);
        float nn = tanhf_(AN + r * AH);
        float hf = (1.f - z) * nn + z * hvv;
        dout[O1 + (size_t)dir * (BATCH * 64) + ((size_t)row << 6) + d] = hf;
        if (dir == 0) {
          dout[((size_t)row << 6) + d] = 0.3f * theta[((size_t)row << 6) + d] + 0.7f * hf;
        }
      }
    }
  };

  STAGE_LOAD(a, Mb0);
  STAGE_WRITE(a, Mb0);
  STAGE_LOAD(b, Mb0 + 64);            // depth-2: tile1 in flight through tile0

  __syncthreads();                    // ABuf(0) + weights + cg2 visible
  compute(Mb0);
  __syncthreads();
  STAGE_WRITE(b, Mb0 + 64);
  STAGE_LOAD(a, Mb0 + 128);

  __syncthreads();
  compute(Mb0 + 64);
  __syncthreads();
  STAGE_WRITE(a, Mb0 + 128);
  STAGE_LOAD(b, Mb0 + 192);

  __syncthreads();
  compute(Mb0 + 128);
  __syncthreads();
  STAGE_WRITE(b, Mb0 + 192);

  __syncthreads();
  compute(Mb0 + 192);
#undef STAGE_LOAD
#undef STAGE_WRITE
#undef ST1
}

// ---------------------------------------------------------------- launch
extern "C" void kernel_launch(void* const* d_in, const int* in_sizes, int n_in,
                              void* d_out, int out_size, void* d_ws, size_t ws_size,
                              hipStream_t stream)
{
  const float* theta   = (const float*)d_in[0];
  const float* context = (const float*)d_in[1];
  const float* h_prev  = (const float*)d_in[2];
  const float* memory  = (const float*)d_in[3];
  const float* tw      = (const float*)d_in[4];
  const float* ipw     = (const float*)d_in[5];
  const float* ipb     = (const float*)d_in[6];
  const float* outw    = (const float*)d_in[7];
  const float* outb    = (const float*)d_in[8];
  const float* ew1     = (const float*)d_in[9];
  const float* eb1     = (const float*)d_in[10];
  const float* ew2     = (const float*)d_in[11];
  const float* eb2     = (const float*)d_in[12];
  const float* pe      = (const float*)d_in[13];
  const float* cw      = (const float*)d_in[14];
  const float* cb      = (const float*)d_in[15];
  const float* iw      = (const float*)d_in[16];
  const float* ib      = (const float*)d_in[17];
  const float* wihf    = (const float*)d_in[18];
  const float* whhf    = (const float*)d_in[19];
  const float* bihf    = (const float*)d_in[20];
  const float* bhhf    = (const float*)d_in[21];
  const float* wihr    = (const float*)d_in[22];
  const float* whhr    = (const float*)d_in[23];
  const float* bihr    = (const float*)d_in[24];
  const float* bhhr    = (const float*)d_in[25];
  const float* fw      = (const float*)d_in[26];
  const float* fb      = (const float*)d_in[27];
  const float* pi      = (const float*)d_in[28];
  float* dout = (float*)d_out;
  float* ws   = (float*)d_ws;

  bool fused = ws_size >= ((size_t)WS_E + (size_t)BATCH * 64) * sizeof(float);
  float* eout = fused ? (ws + WS_E) : (dout + O2);

  kA<<<2, 256, 0, stream>>>(memory, tw, ipw, ipb, outw, outb, wihf, bihf,
                            wihr, bihr, pe, pi, ws);
  if (fused) {
    kW<<<360, 256, 0, stream>>>(cw, iw, pe, ew1, ew2, wihf, whhf, wihr, whhr, ws);
    kB1<1><<<1024, 256, 0, stream>>>(theta, context, cw, cb, iw, ib, pe,
                                     ew1, eb1, ew2, eb2, fw, fb, dout, ws, eout);
    kC<1><<<dim3(256, 2, 1), 256, 0, stream>>>(theta, h_prev, wihf, whhf, bhhf,
                                               wihr, whhr, bhhr, ws, ws + WS_E, dout);
  } else {
    kB1<0><<<1024, 256, 0, stream>>>(theta, context, cw, cb, iw, ib, pe,
                                     ew1, eb1, ew2, eb2, fw, fb, dout, ws, eout);
    kE<<<4096, 256, 0, stream>>>(dout, ws);
    kC<0><<<dim3(256, 2, 1), 256, 0, stream>>>(theta, h_prev, wihf, whhf, bhhf,
                                               wihr, whhr, bhhr, ws, dout + O2, dout);
  }
}

// Round 4
// 356.100 us; speedup vs baseline: 1.2697x; 1.2697x over previous
//
#include <hip/hip_runtime.h>
#include <math.h>

// ---------------------------------------------------------------------------
// REFT_Psi: B=65536 rows, DIM=64.
//  kA  : (grid 2, dir-split) mem-attn -> o_vec -> per-gate GRU constants;
//        G/V/pisq; zeroes stress slots; rowsum(Wih_e) -> WS_WES.
//  kW  : packs all small weights to fp16 in ws.  (fused path only)
//  kB1 : BARRIER-FREE fused kernel (wave owns 16 rows end-to-end); stress
//        partials -> 32 atomic slots.
//  [kE : fallback only: O2 += 0.001*stress]
//  kC  : bi-GRU via MFMA; weights in LDS (one barrier), e/h A-fragments
//        wave-local from global (depth-2 reg sets), rv/ov via shfl,
//        hv fp32 re-read, e_theta written from regs. Waves drift.
// ---------------------------------------------------------------------------

#define BATCH 65536
#define CTXD  384
#define NP    5
#define EPSV  1e-8f

typedef _Float16 h8 __attribute__((ext_vector_type(8)));
typedef _Float16 h4 __attribute__((ext_vector_type(4)));
typedef float f32x4 __attribute__((ext_vector_type(4)));
typedef float f4a __attribute__((ext_vector_type(4)));                 // 16B-aligned
typedef float f4u __attribute__((ext_vector_type(4), aligned(4)));     // 4B-aligned

// output offsets (floats)
#define O0 0
#define O1 4194304
#define O2 12582912
#define O3 16777216
#define O4 16842752
#define O5 16908288

// workspace offsets (floats)
#define WS_SPART  64     // 32 stress partial slots
#define WS_GICF   1536
#define WS_GICR   1792
#define WS_G      2048   // 25 floats: pe@pe^T
#define WS_V      2080   // 5 floats: pe@prev_ideal
#define WS_PISQ   2088   // 1 float
#define WS_WES    2304   // 2x192 floats: rowsum of Wih_e per dir
#define WS_H16F   4096   // fp16 packed weights region (46080 floats)
// halves offsets inside the fp16 region:
#define HCXW  0          // [64][384]   ctx_w
#define HBW   24576      // [16][128]   logits rows: 0-4 iw, 5-9 pe-hi, 10-14 pe-lo
#define HW1   26624      // [128][64]   emo w1
#define HW2   34816      // [64][128]   emo w2
#define HGRU  43008      // per dir 24576: [128][128] (wih_e|whh) | [64][64] WN | [64][64] WHN
#define HTOT  92160
#define WS_E  50176      // raw emotion e [B*64] (fused path only)

__device__ __forceinline__ float sigmoidf_(float x) {
  return 1.f / (1.f + __expf(-x));
}
__device__ __forceinline__ float tanhf_(float x) {
  float e2 = __expf(-2.f * x);
  return 2.f / (1.f + e2) - 1.f;
}
__device__ __forceinline__ h4 cvt4v(f4a v) {
  h4 o = {(_Float16)v[0], (_Float16)v[1], (_Float16)v[2], (_Float16)v[3]};
  return o;
}
__device__ __forceinline__ h8 pack8(f4a u0, f4a u1) {
  h8 b = {(_Float16)u0[0], (_Float16)u0[1], (_Float16)u0[2], (_Float16)u0[3],
          (_Float16)u1[0], (_Float16)u1[1], (_Float16)u1[2], (_Float16)u1[3]};
  return b;
}
__device__ __forceinline__ h8 cvt8p(const float* p) {
  return pack8(*(const f4a*)p, *(const f4a*)(p + 4));
}
__device__ __forceinline__ h8 ldh8(const _Float16* p) { return *(const h8*)p; }

// ---------------------------------------------------------------- kernel A
// grid 2: block 0 = fwd GIC + G/V/pisq + slot zero, block 1 = rev GIC.
__global__ __launch_bounds__(256) void kA(
    const float* __restrict__ memory, const float* __restrict__ tw,
    const float* __restrict__ ipw, const float* __restrict__ ipb,
    const float* __restrict__ outw, const float* __restrict__ outb,
    const float* __restrict__ wihf, const float* __restrict__ bihf,
    const float* __restrict__ wihr, const float* __restrict__ bihr,
    const float* __restrict__ pe, const float* __restrict__ pi,
    float* __restrict__ ws)
{
  __shared__ __align__(16) float attn[16], mth[64], vv[64], ov[64];
  int t = threadIdx.x;
  int dir = blockIdx.x;
  if (t == 0) {
    float m = tw[0];
#pragma unroll
    for (int i = 1; i < 10; i++) m = fmaxf(m, tw[i]);
    float e[10]; float s = 0.f;
#pragma unroll
    for (int i = 0; i < 10; i++) { e[i] = __expf(tw[i] - m); s += e[i]; }
#pragma unroll
    for (int i = 0; i < 10; i++) attn[i] = e[i] / s;
  }
  if (dir == 0) {
    if (t < 25) {
      int l = t / 5, m2 = t - l * 5;
      const f4a* pa = (const f4a*)(pe + l * 64);
      const f4a* pb = (const f4a*)(pe + m2 * 64);
      float s = 0.f;
#pragma unroll
      for (int j = 0; j < 16; j++) {
        f4a a = pa[j], b = pb[j];
        s += a[0]*b[0] + a[1]*b[1] + a[2]*b[2] + a[3]*b[3];
      }
      ws[WS_G + t] = s;
    } else if (t >= 32 && t < 37) {
      int l = t - 32;
      const f4a* pa = (const f4a*)(pe + l * 64);
      const f4a* pb = (const f4a*)pi;
      float s = 0.f;
#pragma unroll
      for (int j = 0; j < 16; j++) {
        f4a a = pa[j], b = pb[j];
        s += a[0]*b[0] + a[1]*b[1] + a[2]*b[2] + a[3]*b[3];
      }
      ws[WS_V + l] = s;
    } else if (t == 40) {
      const f4a* pb = (const f4a*)pi;
      float s = 0.f;
#pragma unroll
      for (int j = 0; j < 16; j++) {
        f4a b = pb[j];
        s += b[0]*b[0] + b[1]*b[1] + b[2]*b[2] + b[3]*b[3];
      }
      ws[WS_PISQ] = s;
    } else if (t >= 64 && t < 96) {
      ws[WS_SPART + t - 64] = 0.f;    // kB1 accumulates atomically
    }
  }
  __syncthreads();
  if (t < 64) {
    float a = 0.f;
#pragma unroll
    for (int m = 0; m < 10; m++) a += attn[m] * memory[m * 64 + t];
    mth[t] = a;
  }
  __syncthreads();
  if (t < 64) {
    const f4a* wr = (const f4a*)(ipw + (size_t)(128 + t) * 64);
    const f4a* mv = (const f4a*)mth;
    float a = ipb[128 + t];
#pragma unroll
    for (int j = 0; j < 16; j++) {
      f4a w = wr[j], o = mv[j];
      a += w[0]*o[0] + w[1]*o[1] + w[2]*o[2] + w[3]*o[3];
    }
    vv[t] = a;
  }
  __syncthreads();
  if (t < 64) {
    const f4a* wr = (const f4a*)(outw + (size_t)t * 64);
    const f4a* mv = (const f4a*)vv;
    float a = outb[t];
#pragma unroll
    for (int j = 0; j < 16; j++) {
      f4a w = wr[j], o = mv[j];
      a += w[0]*o[0] + w[1]*o[1] + w[2]*o[2] + w[3]*o[3];
    }
    ov[t] = a;
  }
  __syncthreads();
  if (t < 192) {
    const float* WIH = dir ? wihr : wihf;
    const float* BIH = dir ? bihr : bihf;
    float a = BIH[t];
    float s2 = 0.f;
    const f4a* ovv = (const f4a*)ov;
#pragma unroll
    for (int j = 0; j < 16; j++) {
      f4u w = *(const f4u*)(WIH + (size_t)t * 130 + j * 4);
      f4a o = ovv[j];
      a += w[0]*o[0] + w[1]*o[1] + w[2]*o[2] + w[3]*o[3];
      f4u w2 = *(const f4u*)(WIH + (size_t)t * 130 + 64 + j * 4);
      s2 += w2[0] + w2[1] + w2[2] + w2[3];
    }
    ws[(dir ? WS_GICR : WS_GICF) + t] = a;
    ws[WS_WES + dir * 192 + t] = s2;
  }
}

// ---------------------------------------------------------------- kernel W
// Packs all small weights to fp16 into ws (grid 360 x 256 = 92160 halves).
__global__ __launch_bounds__(256) void kW(
    const float* __restrict__ cw, const float* __restrict__ iw,
    const float* __restrict__ pe,
    const float* __restrict__ w1, const float* __restrict__ w2,
    const float* __restrict__ wihf, const float* __restrict__ whhf,
    const float* __restrict__ wihr, const float* __restrict__ whhr,
    float* __restrict__ ws)
{
  _Float16* hv = (_Float16*)(ws + WS_H16F);
  int i = blockIdx.x * 256 + threadIdx.x;
  _Float16 v;
  if (i < HBW) {                                   // ctxw [64][384]
    v = (_Float16)cw[i];
  } else if (i < HW1) {                            // logits bw [16][128]
    int i2 = i - HBW;
    int r = i2 >> 7, k = i2 & 127;
    float f = 0.f;
    if (r < 5) f = iw[r * 128 + k];
    else if (r < 10) { if (k < 64) f = pe[(r - 5) * 64 + k]; }
    else if (r < 15) {
      if (k < 64) { float p = pe[(r - 10) * 64 + k]; f = p - (float)(_Float16)p; }
    }
    v = (_Float16)f;
  } else if (i < HW2) {                            // w1 [128][64]
    v = (_Float16)w1[i - HW1];
  } else if (i < HGRU) {                           // w2 [64][128]
    v = (_Float16)w2[i - HW2];
  } else {                                         // GRU, per dir
    int j = i - HGRU;
    int dir = j >= 24576;
    int i2 = j - (dir ? 24576 : 0);
    const float* WIH = dir ? wihr : wihf;
    const float* WHH = dir ? whhr : whhf;
    float f;
    if (i2 < 16384) {
      int n = i2 >> 7, k = i2 & 127;
      f = (k < 64) ? WIH[n * 130 + 64 + k] : WHH[n * 64 + (k - 64)];
    } else if (i2 < 20480) {
      int j2 = i2 - 16384; int n = j2 >> 6, k = j2 & 63;
      f = WIH[(128 + n) * 130 + 64 + k];
    } else {
      int j2 = i2 - 20480; int n = j2 >> 6, k = j2 & 63;
      f = WHH[(128 + n) * 64 + k];
    }
    v = (_Float16)f;
  }
  hv[i] = v;
}

// ---------------------------------------------------------------- kernel B1
// grid 1024, block 256 (4 waves), 64 rows/block, 16 rows/wave.
// ZERO __syncthreads: every LDS buffer is wave-private.
template <int FUSED>
__global__ __launch_bounds__(256, 4) void kB1(
    const float* __restrict__ theta, const float* __restrict__ context,
    const float* __restrict__ ctxw, const float* __restrict__ ctxb,
    const float* __restrict__ idealw, const float* __restrict__ idealb,
    const float* __restrict__ pe,
    const float* __restrict__ w1, const float* __restrict__ b1,
    const float* __restrict__ w2, const float* __restrict__ b2,
    const float* __restrict__ fw, const float* __restrict__ fb,
    float* __restrict__ dout, float* __restrict__ ws,
    float* __restrict__ eout)
{
  __shared__ __align__(16) char R[4 * 5632];
  __shared__ __align__(16) _Float16 cxout[64 * 72];

  int t = threadIdx.x, lane = t & 63, wv = t >> 6;
  int q = lane >> 4, c = lane & 15;
  int Rbase = blockIdx.x << 6;
  int wrow = Rbase + 16 * wv;          // wave's first global row

  char* Rw = R + wv * 5632;
  _Float16* tthhi = (_Float16*)Rw;                 // [16][72]
  _Float16* tthlo = (_Float16*)(Rw + 2304);        // [16][72]
  _Float16* mid   = (_Float16*)Rw;                 // [16][136]
  float*    Lb    = (float*)(Rw + 4352);           // [16][17]
  float*    a0b   = (float*)(Rw + 5440);           // [16]

  const _Float16* hv   = (const _Float16*)(ws + WS_H16F);
  const _Float16* hcxw = hv + HCXW;
  const _Float16* hbw  = hv + HBW;
  const _Float16* hw1  = hv + HW1;
  const _Float16* hw2  = hv + HW2;

  // ---- issue theta loads (wave-local rows) ----
  const f4a* ts = (const f4a*)(theta + (size_t)wrow * 64);
  f4a th0 = ts[lane], th1 = ts[lane + 64], th2 = ts[lane + 128], th3 = ts[lane + 192];

  // ---- issue ctx A-fragment batch 1 (ks 0..5) ----
  const float* crow = context + (size_t)(wrow + c) * CTXD + q * 8;
  f4a a0_[6], a1_[6];
#pragma unroll
  for (int ks = 0; ks < 6; ++ks) {
    a0_[ks] = *(const f4a*)(crow + ks * 32);
    a1_[ks] = *(const f4a*)(crow + ks * 32 + 4);
  }

  // ---- stage theta hi/lo (wave-local; in-wave DS ordering only) ----
  {
#define TST(j, sj) { int sl = (j) * 64 + lane; int row = sl >> 4, pos = sl & 15; \
    h4 hi = cvt4v(sj); \
    f4a lo = {sj[0] - (float)hi[0], sj[1] - (float)hi[1], \
              sj[2] - (float)hi[2], sj[3] - (float)hi[3]}; \
    *(h4*)&tthhi[row * 72 + pos * 4] = hi; \
    *(h4*)&tthlo[row * 72 + pos * 4] = cvt4v(lo); }
    TST(0, th0) TST(1, th1) TST(2, th2) TST(3, th3)
#undef TST
  }

  // ---- convert batch 1, issue+convert batch 2 ----
  h8 af[12];
#pragma unroll
  for (int ks = 0; ks < 6; ++ks) af[ks] = pack8(a0_[ks], a1_[ks]);
#pragma unroll
  for (int ks = 0; ks < 6; ++ks) {
    a0_[ks] = *(const f4a*)(crow + (ks + 6) * 32);
    a1_[ks] = *(const f4a*)(crow + (ks + 6) * 32 + 4);
  }
#pragma unroll
  for (int ks = 0; ks < 6; ++ks) af[6 + ks] = pack8(a0_[ks], a1_[ks]);

  // ---- ctx GEMM: wave owns rows, loops over 4 N-tiles ----
#pragma unroll
  for (int tn = 0; tn < 4; ++tn) {
    f32x4 acc = (f32x4)(0.f);
#pragma unroll
    for (int ks = 0; ks < 12; ++ks) {
      h8 b;
      if constexpr (FUSED) b = ldh8(hcxw + (size_t)(tn * 16 + c) * CTXD + ks * 32 + q * 8);
      else                 b = cvt8p(ctxw + (size_t)(tn * 16 + c) * CTXD + ks * 32 + q * 8);
      acc = __builtin_amdgcn_mfma_f32_16x16x32_f16(af[ks], b, acc, 0, 0, 0);
    }
    float cb = ctxb[tn * 16 + c];
#pragma unroll
    for (int reg = 0; reg < 4; ++reg)
      cxout[(16 * wv + q * 4 + reg) * 72 + tn * 16 + c] = (_Float16)(acc[reg] + cb);
  }

  // ---- B-fragments for logits/tpe GEMM ----
  h8 bw[4];
  if constexpr (FUSED) {
#pragma unroll
    for (int ks = 0; ks < 4; ++ks) bw[ks] = ldh8(hbw + c * 128 + ks * 32 + q * 8);
  } else {
#pragma unroll
    for (int ks = 0; ks < 4; ++ks) {
#pragma unroll
      for (int j = 0; j < 8; ++j) {
        int k = ks * 32 + q * 8 + j;
        float v = 0.f;
        if (c < 5) v = idealw[c * 128 + k];
        else if (c < 10) { if (k < 64) v = pe[(c - 5) * 64 + k]; }
        else if (c < 15) {
          if (k < 64) { float p = pe[(c - 10) * 64 + k]; v = p - (float)(_Float16)p; }
        }
        bw[ks][j] = (_Float16)v;
      }
    }
  }

  // ---- A-fragments (wave-local rows; in-wave DS ordering) ----
  const _Float16* ahp = &tthhi[c * 72 + q * 8];
  const _Float16* alp = &tthlo[c * 72 + q * 8];
  const _Float16* acp = &cxout[(16 * wv + c) * 72 + q * 8];
  h8 ah0 = *(const h8*)(ahp);
  h8 ah1 = *(const h8*)(ahp + 32);
  h8 al0 = *(const h8*)(alp);
  h8 al1 = *(const h8*)(alp + 32);
  h8 ac0 = *(const h8*)(acp);
  h8 ac1 = *(const h8*)(acp + 32);

  // logits + tpe (K = [theta(64) | cx(64)], lo-pass on theta half)
  f32x4 Lacc = (f32x4)(0.f);
  Lacc = __builtin_amdgcn_mfma_f32_16x16x32_f16(ah0, bw[0], Lacc, 0, 0, 0);
  Lacc = __builtin_amdgcn_mfma_f32_16x16x32_f16(ah1, bw[1], Lacc, 0, 0, 0);
  Lacc = __builtin_amdgcn_mfma_f32_16x16x32_f16(ac0, bw[2], Lacc, 0, 0, 0);
  Lacc = __builtin_amdgcn_mfma_f32_16x16x32_f16(ac1, bw[3], Lacc, 0, 0, 0);
  Lacc = __builtin_amdgcn_mfma_f32_16x16x32_f16(al0, bw[0], Lacc, 0, 0, 0);
  Lacc = __builtin_amdgcn_mfma_f32_16x16x32_f16(al1, bw[1], Lacc, 0, 0, 0);
#pragma unroll
  for (int reg = 0; reg < 4; ++reg)
    Lb[(q * 4 + reg) * 17 + c] = Lacc[reg];

  // a0 = ||theta||^2 via diag: hi.hi + 2 hi.lo
  {
    f32x4 hh = (f32x4)(0.f), hl = (f32x4)(0.f);
    hh = __builtin_amdgcn_mfma_f32_16x16x32_f16(ah0, ah0, hh, 0, 0, 0);
    hh = __builtin_amdgcn_mfma_f32_16x16x32_f16(ah1, ah1, hh, 0, 0, 0);
    hl = __builtin_amdgcn_mfma_f32_16x16x32_f16(ah0, al0, hl, 0, 0, 0);
    hl = __builtin_amdgcn_mfma_f32_16x16x32_f16(ah1, al1, hl, 0, 0, 0);
    if ((lane >> 4) == ((lane & 15) >> 2)) {
      int j = lane & 15;
      a0b[j] = hh[j & 3] + 2.f * hl[j & 3];
    }
  }

  // ---- emotion MLP layer 1 (reuses ah0/ah1) ----
#pragma unroll
  for (int tn = 0; tn < 8; ++tn) {
    h8 b0, b1f;
    if constexpr (FUSED) {
      b0  = ldh8(hw1 + (size_t)(tn * 16 + c) * 64 + q * 8);
      b1f = ldh8(hw1 + (size_t)(tn * 16 + c) * 64 + 32 + q * 8);
    } else {
      b0  = cvt8p(w1 + (size_t)(tn * 16 + c) * 64 + q * 8);
      b1f = cvt8p(w1 + (size_t)(tn * 16 + c) * 64 + 32 + q * 8);
    }
    f32x4 a = (f32x4)(0.f);
    a = __builtin_amdgcn_mfma_f32_16x16x32_f16(ah0, b0, a, 0, 0, 0);
    a = __builtin_amdgcn_mfma_f32_16x16x32_f16(ah1, b1f, a, 0, 0, 0);
    float bv = b1[tn * 16 + c];
#pragma unroll
    for (int reg = 0; reg < 4; ++reg)
      mid[(q * 4 + reg) * 136 + tn * 16 + c] = (_Float16)tanhf_(a[reg] + bv);
  }

  // ---- MLP layer 2 (wave-local mid) -> raw e ----
  {
    const _Float16* am = &mid[c * 136 + q * 8];
    h8 m0 = *(const h8*)(am);
    h8 m1 = *(const h8*)(am + 32);
    h8 m2 = *(const h8*)(am + 64);
    h8 m3 = *(const h8*)(am + 96);
#pragma unroll
    for (int tn = 0; tn < 4; ++tn) {
      f32x4 a = (f32x4)(0.f);
#pragma unroll
      for (int ks = 0; ks < 4; ++ks) {
        h8 b;
        if constexpr (FUSED) b = ldh8(hw2 + (size_t)(tn * 16 + c) * 128 + ks * 32 + q * 8);
        else                 b = cvt8p(w2 + (size_t)(tn * 16 + c) * 128 + ks * 32 + q * 8);
        h8 av = (ks == 0) ? m0 : (ks == 1) ? m1 : (ks == 2) ? m2 : m3;
        a = __builtin_amdgcn_mfma_f32_16x16x32_f16(av, b, a, 0, 0, 0);
      }
      float bv = b2[tn * 16 + c];
#pragma unroll
      for (int reg = 0; reg < 4; ++reg) {
        int row = wrow + q * 4 + reg;
        eout[((size_t)row << 6) + tn * 16 + c] = fmaxf(a[reg] + bv, 0.f);  // raw e
      }
    }
  }

  // ---- per-row epilogue (lanes 0-15 own rows wrow+lane) ----
  if (lane < 16) {
    int row = wrow + lane;
    float L[NP], tpe[NP];
#pragma unroll
    for (int l = 0; l < NP; l++) {
      L[l]   = Lb[lane * 17 + l] + idealb[l];
      tpe[l] = Lb[lane * 17 + 5 + l] + Lb[lane * 17 + 10 + l];
    }
    float mx = L[0];
#pragma unroll
    for (int l = 1; l < NP; l++) mx = fmaxf(mx, L[l]);
    float P[NP], s = 0.f;
#pragma unroll
    for (int l = 0; l < NP; l++) { P[l] = __expf(L[l] - mx); s += P[l]; }
    float inv = 1.f / s;
#pragma unroll
    for (int l = 0; l < NP; l++) P[l] *= inv;
#pragma unroll
    for (int l = 0; l < NP; l++) dout[O5 + (size_t)row * NP + l] = P[l];

    float a2 = 0.f, tipi = 0.f;
#pragma unroll
    for (int l = 0; l < NP; l++) {
      a2   += P[l] * tpe[l];
      tipi += P[l] * ws[WS_V + l];
    }
    float a1 = 0.f;
#pragma unroll
    for (int l = 0; l < NP; l++) {
      float pl = P[l];
#pragma unroll
      for (int m = 0; m < NP; m++) a1 += pl * P[m] * ws[WS_G + l * 5 + m];
    }
    float a0 = a0b[lane];
    float a3 = fmaxf(a1 - 2.f * tipi + ws[WS_PISQ], 0.f);

    float na = sqrtf(a0), nb = sqrtf(a1);
    float qq = 1.f / ((na + EPSV) * (nb + EPSV));
    float num = a2 * qq;
    float den = fmaxf(na * nb * qq, EPSV);
    dout[O3 + row] = num / den;
    float fq = sqrtf(a3);
    float om = tanhf_(fq * fw[0] + fb[0]) * (1.f + 0.1f * __sinf(fq));
    dout[O4 + row] = om;

    // stress partial: reduce across the 16 active lanes, one atomic per wave
    float p = a0 - 2.f * a2 + a1;
    p += __shfl_xor(p, 1, 64);
    p += __shfl_xor(p, 2, 64);
    p += __shfl_xor(p, 4, 64);
    p += __shfl_xor(p, 8, 64);
    if (lane == 0) atomicAdd(&ws[WS_SPART + (blockIdx.x & 31)], p);
  }
}

// ---------------------------------------------------------------- kernel E (fallback only)
__global__ __launch_bounds__(256) void kE(float* __restrict__ dout,
                                          const float* __restrict__ ws)
{
  float sc = 0.f;
#pragma unroll
  for (int j = 0; j < 32; ++j) sc += ws[WS_SPART + j];
  sc *= 0.001f;
  int i = blockIdx.x * 256 + threadIdx.x;
  float4* p = (float4*)(dout + O2);
  float4 v = p[i];
  v.x += sc; v.y += sc; v.z += sc; v.w += sc;
  p[i] = v;
}

// ---------------------------------------------------------------- kernel C
// MFMA bi-GRU. grid (256, 2): bx covers 256 rows (4 M-tiles of 64), by=dir.
// Weights in LDS (one barrier); e/h A-fragments wave-local from global with
// depth-2 named reg sets; rv/ov via shfl; hv fp32 re-read (L2-hot); waves
// drift after the single staging barrier.
template <int FUSED>
__global__ __launch_bounds__(256) void kC(
    const float* __restrict__ theta, const float* __restrict__ hprev,
    const float* __restrict__ wihf, const float* __restrict__ whhf,
    const float* __restrict__ bhhf,
    const float* __restrict__ wihr, const float* __restrict__ whhr,
    const float* __restrict__ bhhr,
    const float* __restrict__ ws, const float* __restrict__ esrc,
    float* __restrict__ dout)
{
  __shared__ __align__(16) _Float16 WRZ[128 * 136];   // rows 0-63 R, 64-127 Z; cols 0-63 e-w, 64-127 h-w
  __shared__ __align__(16) _Float16 WNH[64 * 136];    // cols 0-63 WN, 64-127 WHN
  __shared__ float cg2[192], wre[192], wom[192], bhn[64];

  int t = threadIdx.x, lane = t & 63, wv = t >> 6;
  int q = lane >> 4, col = lane & 15;
  int dir = blockIdx.y;
  const float* WIH = dir ? wihr : wihf;
  const float* WHH = dir ? whhr : whhf;
  const float* BHH = dir ? bhhr : bhhf;
  const float* GIC = ws + (dir ? WS_GICR : WS_GICF);

  float sc = 0.f;
#pragma unroll
  for (int j = 0; j < 32; ++j) sc += ws[WS_SPART + j];
  sc *= 0.001f;

  int Mb0 = blockIdx.x << 8;
  int rbase = 16 * wv + col;           // wave-local row offset within a tile

  f4a eA0a, eA1a, eB0a, eB1a, hA0a, hA1a, hB0a, hB1a;
  f4a eA0b, eA1b, eB0b, eB1b, hA0b, hA1b, hB0b, hB1b;
  float rva = 0.f, ova = 0.f, rvb = 0.f, ovb = 0.f;

#define LOADSET(S, mb) do { \
    const float* eb_ = esrc + (((size_t)(mb) + rbase) << 6); \
    const float* hb_ = hprev + (size_t)dir * (BATCH * 64) + (((size_t)(mb) + rbase) << 6); \
    eA0##S = *(const f4a*)(eb_ + q * 8);          eA1##S = *(const f4a*)(eb_ + q * 8 + 4); \
    eB0##S = *(const f4a*)(eb_ + 32 + q * 8);     eB1##S = *(const f4a*)(eb_ + 32 + q * 8 + 4); \
    hA0##S = *(const f4a*)(hb_ + q * 8);          hA1##S = *(const f4a*)(hb_ + q * 8 + 4); \
    hB0##S = *(const f4a*)(hb_ + 32 + q * 8);     hB1##S = *(const f4a*)(hb_ + 32 + q * 8 + 4); \
    if (lane < 16) { rv##S = dout[O3 + (mb) + 16 * wv + lane]; \
                     ov##S = dout[O4 + (mb) + 16 * wv + lane]; } \
  } while (0)

  LOADSET(a, Mb0);
  LOADSET(b, Mb0 + 64);

  // ---- weight staging into LDS ----
  if constexpr (FUSED) {
    const _Float16* gw  = (const _Float16*)(ws + WS_H16F) + HGRU + dir * 24576;
    const _Float16* gRZ = gw;            // [128][128]
    const _Float16* gN  = gw + 16384;    // [64][64]
    const _Float16* gHN = gw + 20480;    // [64][64]
#pragma unroll
    for (int i = 0; i < 8; ++i) {
      int idx = t + i * 256; int n = idx >> 4, c4 = idx & 15;
      *(h8*)&WRZ[n * 136 + c4 * 8] = ldh8(gRZ + (size_t)n * 128 + c4 * 8);
    }
#pragma unroll
    for (int i = 0; i < 4; ++i) {
      int idx = t + i * 256; int n = idx >> 4, c4 = idx & 15;
      if (c4 < 8) *(h8*)&WNH[n * 136 + c4 * 8] = ldh8(gN + (size_t)n * 64 + c4 * 8);
      else        *(h8*)&WNH[n * 136 + 64 + (c4 - 8) * 8] = ldh8(gHN + (size_t)n * 64 + (c4 - 8) * 8);
    }
  } else {
    for (int idx = t; idx < 128 * 32; idx += 256) {
      int n = idx >> 5, g = idx & 31;
      if (g < 16) {
        f4u v = *(const f4u*)(WIH + (size_t)n * 130 + 64 + g * 4);
        h4 o = {(_Float16)v[0], (_Float16)v[1], (_Float16)v[2], (_Float16)v[3]};
        *(h4*)&WRZ[n * 136 + g * 4] = o;
      } else {
        f4a v = *(const f4a*)(WHH + (size_t)n * 64 + (g - 16) * 4);
        *(h4*)&WRZ[n * 136 + 64 + (g - 16) * 4] = cvt4v(v);
      }
    }
    for (int idx = t; idx < 64 * 32; idx += 256) {
      int n = idx >> 5, g = idx & 31;
      if (g < 16) {
        f4u v = *(const f4u*)(WIH + (size_t)(128 + n) * 130 + 64 + g * 4);
        h4 o = {(_Float16)v[0], (_Float16)v[1], (_Float16)v[2], (_Float16)v[3]};
        *(h4*)&WNH[n * 136 + g * 4] = o;
      } else {
        f4a v = *(const f4a*)(WHH + (size_t)(128 + n) * 64 + (g - 16) * 4);
        *(h4*)&WNH[n * 136 + 64 + (g - 16) * 4] = cvt4v(v);
      }
    }
  }
  if (t < 192) {
    wre[t] = WIH[t * 130 + 128];
    wom[t] = WIH[t * 130 + 129];
    cg2[t] = GIC[t] + (t < 128 ? BHH[t] : 0.f) + sc * ws[WS_WES + dir * 192 + t];
  }
  if (t < 64) bhn[t] = BHH[128 + t];
  __syncthreads();                     // weights visible; waves drift from here

  h8 ea0, ea1, ha0, ha1;
  float rv0, rv1, rv2, rv3, ov0, ov1, ov2, ov3;

#define PACKSET(S, mb) do { \
    f4a e0 = eA0##S, e1 = eA1##S, e2 = eB0##S, e3 = eB1##S; \
    if (!FUSED) { e0 = e0 - sc; e1 = e1 - sc; e2 = e2 - sc; e3 = e3 - sc; } \
    else if (dir == 0) { \
      float* ob = dout + O2 + (((size_t)(mb) + rbase) << 6); \
      *(f4a*)(ob + q * 8)          = e0 + sc; \
      *(f4a*)(ob + q * 8 + 4)      = e1 + sc; \
      *(f4a*)(ob + 32 + q * 8)     = e2 + sc; \
      *(f4a*)(ob + 32 + q * 8 + 4) = e3 + sc; \
    } \
    ea0 = pack8(e0, e1); ea1 = pack8(e2, e3); \
    ha0 = pack8(hA0##S, hA1##S); ha1 = pack8(hB0##S, hB1##S); \
    rv0 = __shfl(rv##S, q * 4 + 0, 64); rv1 = __shfl(rv##S, q * 4 + 1, 64); \
    rv2 = __shfl(rv##S, q * 4 + 2, 64); rv3 = __shfl(rv##S, q * 4 + 3, 64); \
    ov0 = __shfl(ov##S, q * 4 + 0, 64); ov1 = __shfl(ov##S, q * 4 + 1, 64); \
    ov2 = __shfl(ov##S, q * 4 + 2, 64); ov3 = __shfl(ov##S, q * 4 + 3, 64); \
  } while (0)

  auto computeTile = [&](int Mbase) {
    f32x4 accR[4], accZ[4], accN[4], accH[4];
#pragma unroll
    for (int td = 0; td < 4; td++) {
      accR[td] = (f32x4)(0.f); accZ[td] = (f32x4)(0.f);
      accN[td] = (f32x4)(0.f); accH[td] = (f32x4)(0.f);
    }
#pragma unroll
    for (int td = 0; td < 4; td++) {
      int n = td * 16 + col;
      const _Float16* br = &WRZ[n * 136 + q * 8];
      accR[td] = __builtin_amdgcn_mfma_f32_16x16x32_f16(ea0, ldh8(br),      accR[td], 0, 0, 0);
      accR[td] = __builtin_amdgcn_mfma_f32_16x16x32_f16(ea1, ldh8(br + 32), accR[td], 0, 0, 0);
      accR[td] = __builtin_amdgcn_mfma_f32_16x16x32_f16(ha0, ldh8(br + 64), accR[td], 0, 0, 0);
      accR[td] = __builtin_amdgcn_mfma_f32_16x16x32_f16(ha1, ldh8(br + 96), accR[td], 0, 0, 0);
      const _Float16* bz = &WRZ[(64 + n) * 136 + q * 8];
      accZ[td] = __builtin_amdgcn_mfma_f32_16x16x32_f16(ea0, ldh8(bz),      accZ[td], 0, 0, 0);
      accZ[td] = __builtin_amdgcn_mfma_f32_16x16x32_f16(ea1, ldh8(bz + 32), accZ[td], 0, 0, 0);
      accZ[td] = __builtin_amdgcn_mfma_f32_16x16x32_f16(ha0, ldh8(bz + 64), accZ[td], 0, 0, 0);
      accZ[td] = __builtin_amdgcn_mfma_f32_16x16x32_f16(ha1, ldh8(bz + 96), accZ[td], 0, 0, 0);
      const _Float16* bn = &WNH[n * 136 + q * 8];
      accN[td] = __builtin_amdgcn_mfma_f32_16x16x32_f16(ea0, ldh8(bn),      accN[td], 0, 0, 0);
      accN[td] = __builtin_amdgcn_mfma_f32_16x16x32_f16(ea1, ldh8(bn + 32), accN[td], 0, 0, 0);
      const _Float16* bh = &WNH[n * 136 + 64 + q * 8];
      accH[td] = __builtin_amdgcn_mfma_f32_16x16x32_f16(ha0, ldh8(bh),      accH[td], 0, 0, 0);
      accH[td] = __builtin_amdgcn_mfma_f32_16x16x32_f16(ha1, ldh8(bh + 32), accH[td], 0, 0, 0);
    }
#pragma unroll
    for (int reg = 0; reg < 4; reg++) {
      int lr  = 16 * wv + q * 4 + reg;
      int row = Mbase + lr;
      float rv  = (reg == 0) ? rv0 : (reg == 1) ? rv1 : (reg == 2) ? rv2 : rv3;
      float ovv = (reg == 0) ? ov0 : (reg == 1) ? ov1 : (reg == 2) ? ov2 : ov3;
#pragma unroll
      for (int td = 0; td < 4; td++) {
        int d = td * 16 + col;
        float hvv = hprev[(size_t)dir * (BATCH * 64) + ((size_t)row << 6) + d];
        float A0 = accR[td][reg] + cg2[d]       + rv * wre[d]       + ovv * wom[d];
        float A1 = accZ[td][reg] + cg2[64 + d]  + rv * wre[64 + d]  + ovv * wom[64 + d];
        float AN = accN[td][reg] + cg2[128 + d] + rv * wre[128 + d] + ovv * wom[128 + d];
        float AH = accH[td][reg] + bhn[d];
        float r  = sigmoidf_(A0);
        float z  = sigmoidf_(A1);
        float nn = tanhf_(AN + r * AH);
        float hf = (1.f - z) * nn + z * hvv;
        dout[O1 + (size_t)dir * (BATCH * 64) + ((size_t)row << 6) + d] = hf;
        if (dir == 0) {
          dout[((size_t)row << 6) + d] = 0.3f * theta[((size_t)row << 6) + d] + 0.7f * hf;
        }
      }
    }
  };

  PACKSET(a, Mb0);        LOADSET(a, Mb0 + 128);  computeTile(Mb0);
  PACKSET(b, Mb0 + 64);   LOADSET(b, Mb0 + 192);  computeTile(Mb0 + 64);
  PACKSET(a, Mb0 + 128);                          computeTile(Mb0 + 128);
  PACKSET(b, Mb0 + 192);                          computeTile(Mb0 + 192);
#undef LOADSET
#undef PACKSET
}

// ---------------------------------------------------------------- launch
extern "C" void kernel_launch(void* const* d_in, const int* in_sizes, int n_in,
                              void* d_out, int out_size, void* d_ws, size_t ws_size,
                              hipStream_t stream)
{
  const float* theta   = (const float*)d_in[0];
  const float* context = (const float*)d_in[1];
  const float* h_prev  = (const float*)d_in[2];
  const float* memory  = (const float*)d_in[3];
  const float* tw      = (const float*)d_in[4];
  const float* ipw     = (const float*)d_in[5];
  const float* ipb     = (const float*)d_in[6];
  const float* outw    = (const float*)d_in[7];
  const float* outb    = (const float*)d_in[8];
  const float* ew1     = (const float*)d_in[9];
  const float* eb1     = (const float*)d_in[10];
  const float* ew2     = (const float*)d_in[11];
  const float* eb2     = (const float*)d_in[12];
  const float* pe      = (const float*)d_in[13];
  const float* cw      = (const float*)d_in[14];
  const float* cb      = (const float*)d_in[15];
  const float* iw      = (const float*)d_in[16];
  const float* ib      = (const float*)d_in[17];
  const float* wihf    = (const float*)d_in[18];
  const float* whhf    = (const float*)d_in[19];
  const float* bihf    = (const float*)d_in[20];
  const float* bhhf    = (const float*)d_in[21];
  const float* wihr    = (const float*)d_in[22];
  const float* whhr    = (const float*)d_in[23];
  const float* bihr    = (const float*)d_in[24];
  const float* bhhr    = (const float*)d_in[25];
  const float* fw      = (const float*)d_in[26];
  const float* fb      = (const float*)d_in[27];
  const float* pi      = (const float*)d_in[28];
  float* dout = (float*)d_out;
  float* ws   = (float*)d_ws;

  bool fused = ws_size >= ((size_t)WS_E + (size_t)BATCH * 64) * sizeof(float);
  float* eout = fused ? (ws + WS_E) : (dout + O2);

  kA<<<2, 256, 0, stream>>>(memory, tw, ipw, ipb, outw, outb, wihf, bihf,
                            wihr, bihr, pe, pi, ws);
  if (fused) {
    kW<<<360, 256, 0, stream>>>(cw, iw, pe, ew1, ew2, wihf, whhf, wihr, whhr, ws);
    kB1<1><<<1024, 256, 0, stream>>>(theta, context, cw, cb, iw, ib, pe,
                                     ew1, eb1, ew2, eb2, fw, fb, dout, ws, eout);
    kC<1><<<dim3(256, 2, 1), 256, 0, stream>>>(theta, h_prev, wihf, whhf, bhhf,
                                               wihr, whhr, bhhr, ws, ws + WS_E, dout);
  } else {
    kB1<0><<<1024, 256, 0, stream>>>(theta, context, cw, cb, iw, ib, pe,
                                     ew1, eb1, ew2, eb2, fw, fb, dout, ws, eout);
    kE<<<4096, 256, 0, stream>>>(dout, ws);
    kC<0><<<dim3(256, 2, 1), 256, 0, stream>>>(theta, h_prev, wihf, whhf, bhhf,
                                               wihr, whhr, bhhr, ws, dout + O2, dout);
  }
}